// Round 1
// baseline (852.602 us; speedup 1.0000x reference)
//
#include <hip/hip_runtime.h>
#include <hip/hip_bf16.h>

#define NN 100000
#define NE 1000000

static __device__ __forceinline__ float bf2f(unsigned short u){
  unsigned int x = ((unsigned int)u) << 16;
  return __uint_as_float(x);
}
static __device__ __forceinline__ unsigned short f2bf(float f){
  unsigned int x = __float_as_uint(f);
  unsigned int r = (x + 0x7fffu + ((x >> 16) & 1u)) >> 16;
  return (unsigned short)r;
}

// ---------------- CSR build ----------------

__global__ void k_degree(const int* __restrict__ dst, int* __restrict__ cnt, int E){
  int e = blockIdx.x * blockDim.x + threadIdx.x;
  if (e < E) atomicAdd(&cnt[dst[e]], 1);
}

__global__ void k_chunk_sum(const int* __restrict__ cnt, int* __restrict__ partials, int N){
  __shared__ int sw[16];
  int b = blockIdx.x, t = threadIdx.x;
  int i = b * 1024 + t;
  int v = (i < N) ? cnt[i] : 0;
  #pragma unroll
  for (int off = 32; off; off >>= 1) v += __shfl_xor(v, off);
  int lane = t & 63, w = t >> 6;
  if (lane == 0) sw[w] = v;
  __syncthreads();
  if (t < 16){
    int s = sw[t];
    #pragma unroll
    for (int off = 8; off; off >>= 1) s += __shfl_xor(s, off);
    if (t == 0) partials[b] = s;
  }
}

__global__ void k_scan_partials(const int* __restrict__ partials, int* __restrict__ bases, int nchunk){
  if (threadIdx.x == 0 && blockIdx.x == 0){
    int run = 0;
    for (int j = 0; j < nchunk; j++){ bases[j] = run; run += partials[j]; }
  }
}

__global__ void k_chunk_scan(const int* __restrict__ cnt, const int* __restrict__ bases,
                             int* __restrict__ offs, int* __restrict__ cursor,
                             float* __restrict__ deginv, int N){
  __shared__ int sd[1024];
  int b = blockIdx.x, t = threadIdx.x;
  int i = b * 1024 + t;
  int v = (i < N) ? cnt[i] : 0;
  sd[t] = v;
  __syncthreads();
  for (int off = 1; off < 1024; off <<= 1){
    int x = (t >= off) ? sd[t - off] : 0;
    __syncthreads();
    sd[t] += x;
    __syncthreads();
  }
  if (i < N){
    int excl = bases[b] + sd[t] - v;
    offs[i] = excl;
    cursor[i] = excl;
    deginv[i] = (v > 0) ? (1.0f / (float)v) : 0.0f;
  }
}

__global__ void k_fill(const int* __restrict__ src, const int* __restrict__ dst,
                       int* __restrict__ cursor, int* __restrict__ csr, int E){
  int e = blockIdx.x * blockDim.x + threadIdx.x;
  if (e < E){
    int p = atomicAdd(&cursor[dst[e]], 1);
    csr[p] = src[e];
  }
}

// ---------------- Dual GEMM: out_l = in @ Wl, out_r = in @ Wr (bf16 outputs) ----------------
// in: [N,256] (f32 or bf16), Wl/Wr: [256, OUTH] f32, out: [N, OUTH] bf16
// block: 32 nodes, OUTH threads (one output column of each of Wl,Wr per thread)

template<int OUTH, bool INBF>
__launch_bounds__(OUTH)
__global__ void k_gemm_dual(const void* __restrict__ inp,
                            const float* __restrict__ Wl,
                            const float* __restrict__ Wr,
                            unsigned short* __restrict__ outl,
                            unsigned short* __restrict__ outr)
{
  __shared__ float sA[8][32];
  const int t = threadIdx.x;
  const size_t n0 = (size_t)blockIdx.x * 32;
  float accl[32], accr[32];
  #pragma unroll
  for (int n = 0; n < 32; n++){ accl[n] = 0.f; accr[n] = 0.f; }

  for (int k0 = 0; k0 < 256; k0 += 8){
    __syncthreads();
    for (int i = t; i < 256; i += OUTH){
      int r = i >> 3, c = i & 7;
      float v;
      if (INBF) v = bf2f(((const unsigned short*)inp)[(n0 + r) * 256 + k0 + c]);
      else      v = ((const float*)inp)[(n0 + r) * 256 + k0 + c];
      sA[c][r] = v;
    }
    __syncthreads();
    #pragma unroll
    for (int kk = 0; kk < 8; kk++){
      float wl = Wl[(k0 + kk) * OUTH + t];
      float wr = Wr[(k0 + kk) * OUTH + t];
      const float4* row = (const float4*)(&sA[kk][0]);
      #pragma unroll
      for (int q = 0; q < 8; q++){
        float4 a = row[q];
        accl[q*4+0] += a.x * wl; accl[q*4+1] += a.y * wl;
        accl[q*4+2] += a.z * wl; accl[q*4+3] += a.w * wl;
        accr[q*4+0] += a.x * wr; accr[q*4+1] += a.y * wr;
        accr[q*4+2] += a.z * wr; accr[q*4+3] += a.w * wr;
      }
    }
  }
  #pragma unroll
  for (int n = 0; n < 32; n++){
    outl[(n0 + n) * OUTH + t] = f2bf(accl[n]);
    outr[(n0 + n) * OUTH + t] = f2bf(accr[n]);
  }
}

// ---------------- Aggregation epilogues ----------------
// h[n,:] = relu(deginv[n] * sum_{s in N(n)} q1[s,:] + r1[n,:] + b1)  (256-wide)

__global__ void k_agg1(const unsigned short* __restrict__ q1,
                       const unsigned short* __restrict__ r1,
                       const float* __restrict__ b1,
                       const int* __restrict__ offs, const int* __restrict__ cnt,
                       const float* __restrict__ deginv,
                       const int* __restrict__ csr,
                       unsigned short* __restrict__ h, int N)
{
  int wv = threadIdx.x >> 6, lane = threadIdx.x & 63;
  int n = blockIdx.x * 4 + wv;
  if (n >= N) return;
  int beg = offs[n], d = cnt[n];
  float a0 = 0.f, a1 = 0.f, a2 = 0.f, a3 = 0.f;
  for (int j = 0; j < d; j++){
    int s = csr[beg + j];
    ushort4 v = *(const ushort4*)(q1 + (size_t)s * 256 + lane * 4);
    a0 += bf2f(v.x); a1 += bf2f(v.y); a2 += bf2f(v.z); a3 += bf2f(v.w);
  }
  float di = deginv[n];
  ushort4 rv = *(const ushort4*)(r1 + (size_t)n * 256 + lane * 4);
  float4 bv = *(const float4*)(b1 + lane * 4);
  ushort4 o;
  o.x = f2bf(fmaxf(a0 * di + bf2f(rv.x) + bv.x, 0.f));
  o.y = f2bf(fmaxf(a1 * di + bf2f(rv.y) + bv.y, 0.f));
  o.z = f2bf(fmaxf(a2 * di + bf2f(rv.z) + bv.z, 0.f));
  o.w = f2bf(fmaxf(a3 * di + bf2f(rv.w) + bv.w, 0.f));
  *(ushort4*)(h + (size_t)n * 256 + lane * 4) = o;
}

// h2[n,:] = relu(deginv[n] * sum p2[s,:] + r2[n,:] + b2)  (128-wide, f32 out)

__global__ void k_agg2(const unsigned short* __restrict__ p2,
                       const unsigned short* __restrict__ r2,
                       const float* __restrict__ b2,
                       const int* __restrict__ offs, const int* __restrict__ cnt,
                       const float* __restrict__ deginv,
                       const int* __restrict__ csr,
                       float* __restrict__ h2, int N)
{
  int wv = threadIdx.x >> 6, lane = threadIdx.x & 63;
  int n = blockIdx.x * 4 + wv;
  if (n >= N) return;
  int beg = offs[n], d = cnt[n];
  float a0 = 0.f, a1 = 0.f;
  for (int j = 0; j < d; j++){
    int s = csr[beg + j];
    ushort2 v = *(const ushort2*)(p2 + (size_t)s * 128 + lane * 2);
    a0 += bf2f(v.x); a1 += bf2f(v.y);
  }
  float di = deginv[n];
  ushort2 rv = *(const ushort2*)(r2 + (size_t)n * 128 + lane * 2);
  float2 bv = *(const float2*)(b2 + lane * 2);
  float2 o;
  o.x = fmaxf(a0 * di + bf2f(rv.x) + bv.x, 0.f);
  o.y = fmaxf(a1 * di + bf2f(rv.y) + bv.y, 0.f);
  *(float2*)(h2 + (size_t)n * 128 + lane * 2) = o;
}

// ---------------- Classifier + log_softmax ----------------

__global__ void k_cls(const float* __restrict__ h2, const float* __restrict__ Wc,
                      const float* __restrict__ bc, float* __restrict__ out, int N)
{
  int wv = threadIdx.x >> 6, lane = threadIdx.x & 63;
  int n = blockIdx.x * 4 + wv;
  if (n >= N) return;
  float2 hv = *(const float2*)(h2 + (size_t)n * 128 + lane * 2);
  float4 wcv = *(const float4*)(Wc + lane * 4);
  float p0 = hv.x * wcv.x + hv.y * wcv.z;
  float p1 = hv.x * wcv.y + hv.y * wcv.w;
  #pragma unroll
  for (int off = 32; off; off >>= 1){
    p0 += __shfl_xor(p0, off);
    p1 += __shfl_xor(p1, off);
  }
  if (lane == 0){
    float z0 = p0 + bc[0], z1 = p1 + bc[1];
    float m = fmaxf(z0, z1);
    float lse = m + logf(expf(z0 - m) + expf(z1 - m));
    out[(size_t)n * 2 + 0] = z0 - lse;
    out[(size_t)n * 2 + 1] = z1 - lse;
  }
}

// ---------------- host launch ----------------

extern "C" void kernel_launch(void* const* d_in, const int* in_sizes, int n_in,
                              void* d_out, int out_size, void* d_ws, size_t ws_size,
                              hipStream_t stream)
{
  const float* x   = (const float*)d_in[0];
  const int*   ei  = (const int*)d_in[1];
  const float* W1l = (const float*)d_in[2];
  const float* W1r = (const float*)d_in[3];
  const float* b1  = (const float*)d_in[4];
  const float* W2l = (const float*)d_in[5];
  const float* W2r = (const float*)d_in[6];
  const float* b2  = (const float*)d_in[7];
  const float* Wc  = (const float*)d_in[8];
  const float* bc  = (const float*)d_in[9];
  float* out = (float*)d_out;

  const int N = NN, E = NE;
  const int* src = ei;
  const int* dst = ei + E;

  char* ws = (char*)d_ws;
  size_t off = 0;
  auto alloc = [&](size_t bytes) -> void* {
    void* p = ws + off;
    off += (bytes + 255) & ~(size_t)255;
    return p;
  };
  int*   cnt      = (int*)alloc((size_t)N * 4);
  int*   offs     = (int*)alloc((size_t)N * 4);
  int*   cursor   = (int*)alloc((size_t)N * 4);
  float* deginv   = (float*)alloc((size_t)N * 4);
  int*   partials = (int*)alloc(1024);
  int*   bases    = (int*)alloc(1024);
  int*   csr      = (int*)alloc((size_t)E * 4);
  unsigned short* q1 = (unsigned short*)alloc((size_t)N * 256 * 2);
  unsigned short* r1 = (unsigned short*)alloc((size_t)N * 256 * 2);
  unsigned short* h  = (unsigned short*)alloc((size_t)N * 256 * 2);
  // layer-2 buffers alias layer-1 projection buffers (free after h is built)
  unsigned short* p2 = q1;                          // N*128 bf16
  unsigned short* r2 = q1 + (size_t)N * 128;        // N*128 bf16
  float*          h2 = (float*)r1;                  // N*128 f32 (same bytes as r1 region)

  (void)in_sizes; (void)n_in; (void)out_size; (void)ws_size;

  hipMemsetAsync(cnt, 0, (size_t)N * 4, stream);

  int nchunk = (N + 1023) / 1024;
  k_degree<<<(E + 255) / 256, 256, 0, stream>>>(dst, cnt, E);
  k_chunk_sum<<<nchunk, 1024, 0, stream>>>(cnt, partials, N);
  k_scan_partials<<<1, 64, 0, stream>>>(partials, bases, nchunk);
  k_chunk_scan<<<nchunk, 1024, 0, stream>>>(cnt, bases, offs, cursor, deginv, N);
  k_fill<<<(E + 255) / 256, 256, 0, stream>>>(src, dst, cursor, csr, E);

  // layer 1: q1 = x@W1l, r1 = x@W1r ; h = relu(deginv*agg(q1) + r1 + b1)
  k_gemm_dual<256, false><<<N / 32, 256, 0, stream>>>(x, W1l, W1r, q1, r1);
  k_agg1<<<N / 4, 256, 0, stream>>>(q1, r1, b1, offs, cnt, deginv, csr, h, N);

  // layer 2: p2 = h@W2l, r2 = h@W2r ; h2 = relu(deginv*agg(p2) + r2 + b2)
  k_gemm_dual<128, true><<<N / 32, 128, 0, stream>>>(h, W2l, W2r, p2, r2);
  k_agg2<<<N / 4, 256, 0, stream>>>(p2, r2, b2, offs, cnt, deginv, csr, h2, N);

  // classifier + log_softmax
  k_cls<<<N / 4, 256, 0, stream>>>(h2, Wc, bc, out, N);
}

// Round 2
// 474.780 us; speedup vs baseline: 1.7958x; 1.7958x over previous
//
#include <hip/hip_runtime.h>
#include <hip/hip_bf16.h>

#define NN 100000
#define NE 1000000
#define MPAD 100096   // 782*128

typedef __attribute__((ext_vector_type(8))) short bf16x8;
typedef __attribute__((ext_vector_type(4))) float f32x4;
typedef __attribute__((ext_vector_type(8))) unsigned short us8;

static __device__ __forceinline__ float bf2f(unsigned short u){
  unsigned int x = ((unsigned int)u) << 16;
  return __uint_as_float(x);
}
static __device__ __forceinline__ unsigned short f2bf(float f){
  unsigned int x = __float_as_uint(f);
  unsigned int r = (x + 0x7fffu + ((x >> 16) & 1u)) >> 16;
  return (unsigned short)r;
}
static __device__ __forceinline__ void gld16(const void* g, void* l){
  __builtin_amdgcn_global_load_lds((const __attribute__((address_space(1))) void*)g,
                                   (__attribute__((address_space(3))) void*)l, 16, 0, 0);
}

// ---------------- CSR build ----------------

__global__ void k_degree(const int* __restrict__ dst, int* __restrict__ cnt, int E){
  int e = blockIdx.x * blockDim.x + threadIdx.x;
  if (e < E) atomicAdd(&cnt[dst[e]], 1);
}

__global__ void k_chunk_sum(const int* __restrict__ cnt, int* __restrict__ partials, int N){
  __shared__ int sw[16];
  int b = blockIdx.x, t = threadIdx.x;
  int i = b * 1024 + t;
  int v = (i < N) ? cnt[i] : 0;
  #pragma unroll
  for (int off = 32; off; off >>= 1) v += __shfl_xor(v, off);
  int lane = t & 63, w = t >> 6;
  if (lane == 0) sw[w] = v;
  __syncthreads();
  if (t < 16){
    int s = sw[t];
    #pragma unroll
    for (int off = 8; off; off >>= 1) s += __shfl_xor(s, off);
    if (t == 0) partials[b] = s;
  }
}

__global__ void k_scan_partials(const int* __restrict__ partials, int* __restrict__ bases, int nchunk){
  if (threadIdx.x == 0 && blockIdx.x == 0){
    int run = 0;
    for (int j = 0; j < nchunk; j++){ bases[j] = run; run += partials[j]; }
  }
}

__global__ void k_chunk_scan(const int* __restrict__ cnt, const int* __restrict__ bases,
                             int* __restrict__ offs, int* __restrict__ cursor,
                             float* __restrict__ deginv, int N){
  __shared__ int sd[1024];
  int b = blockIdx.x, t = threadIdx.x;
  int i = b * 1024 + t;
  int v = (i < N) ? cnt[i] : 0;
  sd[t] = v;
  __syncthreads();
  for (int off = 1; off < 1024; off <<= 1){
    int x = (t >= off) ? sd[t - off] : 0;
    __syncthreads();
    sd[t] += x;
    __syncthreads();
  }
  if (i < N){
    int excl = bases[b] + sd[t] - v;
    offs[i] = excl;
    cursor[i] = excl;
    deginv[i] = (v > 0) ? (1.0f / (float)v) : 0.0f;
  }
}

__global__ void k_fill(const int* __restrict__ src, const int* __restrict__ dst,
                       int* __restrict__ cursor, int* __restrict__ csr, int E){
  int e = blockIdx.x * blockDim.x + threadIdx.x;
  if (e < E){
    int p = atomicAdd(&cursor[dst[e]], 1);
    csr[p] = src[e];
  }
}

// ---------------- input cast + pad: x f32 -> xb bf16 [MPAD][256] ----------------

__global__ void k_cvt(const float* __restrict__ x, unsigned short* __restrict__ xb){
  size_t i = ((size_t)blockIdx.x * 256 + threadIdx.x) * 8;
  if (i >= (size_t)MPAD * 256) return;
  int row = (int)(i >> 8);
  us8 o;
  if (row < NN){
    const float4* p = (const float4*)(x + i);
    float4 a = p[0], b = p[1];
    o[0]=f2bf(a.x); o[1]=f2bf(a.y); o[2]=f2bf(a.z); o[3]=f2bf(a.w);
    o[4]=f2bf(b.x); o[5]=f2bf(b.y); o[6]=f2bf(b.z); o[7]=f2bf(b.w);
  } else {
    #pragma unroll
    for (int j = 0; j < 8; j++) o[j] = 0;
  }
  *(us8*)(xb + i) = o;
}

// ---------------- weight prep: Bt[n][k] bf16 (transposed, cols concatenated) ----------------

__global__ void k_prep_w(const float* __restrict__ W1l, const float* __restrict__ W1r,
                         const float* __restrict__ W2l, const float* __restrict__ W2r,
                         unsigned short* __restrict__ Bt1, unsigned short* __restrict__ Bt2){
  int i = blockIdx.x * 256 + threadIdx.x;
  if (i < 512 * 256){
    int n = i >> 8, k = i & 255;
    float v = (n < 256) ? W1l[k * 256 + n] : W1r[k * 256 + (n - 256)];
    Bt1[n * 256 + k] = f2bf(v);
  }
  if (i < 256 * 256){
    int n = i >> 8, k = i & 255;
    float v = (n < 128) ? W2l[k * 128 + n] : W2r[k * 128 + (n - 128)];
    Bt2[n * 256 + k] = f2bf(v);
  }
}

// ---------------- MFMA GEMM: C[M][Nout] = A[M][256] @ Bt[Nout][256]^T (all bf16) ----------------
// 128x128 tile, BK=64, 4 waves (each 64x64), global_load_lds staging with
// XOR chunk-swizzle (source-side pre-swizzle, same XOR on ds_read).

__global__ __launch_bounds__(256)
void k_gemm(const unsigned short* __restrict__ A,
            const unsigned short* __restrict__ Bt,
            unsigned short* __restrict__ C,
            int Nout)
{
  __shared__ __align__(16) unsigned short lA[128 * 64];
  __shared__ __align__(16) unsigned short lB[128 * 64];
  const int t = threadIdx.x;
  const int lane = t & 63, wid = t >> 6;
  const int wm = wid >> 1, wn = wid & 1;
  const int m0 = blockIdx.x * 128;
  const int n0 = blockIdx.y * 128;

  f32x4 acc[4][4] = {};

  const int strow = wid * 32 + (lane >> 3);            // + s4*8
  const int sc    = (lane & 7) ^ ((lane >> 3) & 7);    // swizzled source chunk

  for (int kt = 0; kt < 4; ++kt){
    __syncthreads();
    #pragma unroll
    for (int s4 = 0; s4 < 4; ++s4){
      int row = strow + s4 * 8;
      gld16(A  + (size_t)(m0 + row) * 256 + kt * 64 + sc * 8, &lA[(wid * 4 + s4) * 512]);
      gld16(Bt + (size_t)(n0 + row) * 256 + kt * 64 + sc * 8, &lB[(wid * 4 + s4) * 512]);
    }
    __syncthreads();
    #pragma unroll
    for (int ks = 0; ks < 2; ++ks){
      bf16x8 av[4], bv[4];
      const int kc = ks * 4 + (lane >> 4);
      #pragma unroll
      for (int m = 0; m < 4; m++){
        int r = wm * 64 + m * 16 + (lane & 15);
        av[m] = *(const bf16x8*)&lA[r * 64 + ((kc ^ (r & 7)) << 3)];
      }
      #pragma unroll
      for (int n = 0; n < 4; n++){
        int c = wn * 64 + n * 16 + (lane & 15);
        bv[n] = *(const bf16x8*)&lB[c * 64 + ((kc ^ (c & 7)) << 3)];
      }
      #pragma unroll
      for (int m = 0; m < 4; m++)
        #pragma unroll
        for (int n = 0; n < 4; n++)
          acc[m][n] = __builtin_amdgcn_mfma_f32_16x16x32_bf16(av[m], bv[n], acc[m][n], 0, 0, 0);
    }
  }

  const int crow0 = m0 + wm * 64 + (lane >> 4) * 4;
  const int ccol0 = n0 + wn * 64 + (lane & 15);
  #pragma unroll
  for (int m = 0; m < 4; m++){
    #pragma unroll
    for (int r = 0; r < 4; r++){
      size_t rowoff = (size_t)(crow0 + m * 16 + r) * Nout;
      #pragma unroll
      for (int n = 0; n < 4; n++)
        C[rowoff + ccol0 + n * 16] = f2bf(acc[m][n][r]);
    }
  }
}

// ---------------- Aggregation epilogues ----------------
// h[n,:] = relu(deginv[n]*sum_{s in N(n)} q1[s,:] + r1[n,:] + b1); C1=[MPAD][512] (q1|r1)

__global__ void k_agg1(const unsigned short* __restrict__ C1,
                       const float* __restrict__ b1,
                       const int* __restrict__ offs, const int* __restrict__ cnt,
                       const float* __restrict__ deginv,
                       const int* __restrict__ csr,
                       unsigned short* __restrict__ h, int N)
{
  int wv = threadIdx.x >> 6, lane = threadIdx.x & 63;
  int n = blockIdx.x * 4 + wv;
  if (n >= N) return;
  int beg = offs[n], d = cnt[n];
  float a0 = 0.f, a1 = 0.f, a2 = 0.f, a3 = 0.f;
  for (int j = 0; j < d; j++){
    int s = csr[beg + j];
    ushort4 v = *(const ushort4*)(C1 + (size_t)s * 512 + lane * 4);
    a0 += bf2f(v.x); a1 += bf2f(v.y); a2 += bf2f(v.z); a3 += bf2f(v.w);
  }
  float di = deginv[n];
  ushort4 rv = *(const ushort4*)(C1 + (size_t)n * 512 + 256 + lane * 4);
  float4 bv = *(const float4*)(b1 + lane * 4);
  ushort4 o;
  o.x = f2bf(fmaxf(a0 * di + bf2f(rv.x) + bv.x, 0.f));
  o.y = f2bf(fmaxf(a1 * di + bf2f(rv.y) + bv.y, 0.f));
  o.z = f2bf(fmaxf(a2 * di + bf2f(rv.z) + bv.z, 0.f));
  o.w = f2bf(fmaxf(a3 * di + bf2f(rv.w) + bv.w, 0.f));
  *(ushort4*)(h + (size_t)n * 256 + lane * 4) = o;
}

// h2[n,:] = relu(deginv[n]*sum p2[s,:] + r2[n,:] + b2); C2=[MPAD][256] (p2|r2), h2 f32 [N][128]

__global__ void k_agg2(const unsigned short* __restrict__ C2,
                       const float* __restrict__ b2,
                       const int* __restrict__ offs, const int* __restrict__ cnt,
                       const float* __restrict__ deginv,
                       const int* __restrict__ csr,
                       float* __restrict__ h2, int N)
{
  int wv = threadIdx.x >> 6, lane = threadIdx.x & 63;
  int n = blockIdx.x * 4 + wv;
  if (n >= N) return;
  int beg = offs[n], d = cnt[n];
  float a0 = 0.f, a1 = 0.f;
  for (int j = 0; j < d; j++){
    int s = csr[beg + j];
    ushort2 v = *(const ushort2*)(C2 + (size_t)s * 256 + lane * 2);
    a0 += bf2f(v.x); a1 += bf2f(v.y);
  }
  float di = deginv[n];
  ushort2 rv = *(const ushort2*)(C2 + (size_t)n * 256 + 128 + lane * 2);
  float2 bv = *(const float2*)(b2 + lane * 2);
  float2 o;
  o.x = fmaxf(a0 * di + bf2f(rv.x) + bv.x, 0.f);
  o.y = fmaxf(a1 * di + bf2f(rv.y) + bv.y, 0.f);
  *(float2*)(h2 + (size_t)n * 128 + lane * 2) = o;
}

// ---------------- Classifier + log_softmax ----------------

__global__ void k_cls(const float* __restrict__ h2, const float* __restrict__ Wc,
                      const float* __restrict__ bc, float* __restrict__ out, int N)
{
  int wv = threadIdx.x >> 6, lane = threadIdx.x & 63;
  int n = blockIdx.x * 4 + wv;
  if (n >= N) return;
  float2 hv = *(const float2*)(h2 + (size_t)n * 128 + lane * 2);
  float4 wcv = *(const float4*)(Wc + lane * 4);
  float p0 = hv.x * wcv.x + hv.y * wcv.z;
  float p1 = hv.x * wcv.y + hv.y * wcv.w;
  #pragma unroll
  for (int off = 32; off; off >>= 1){
    p0 += __shfl_xor(p0, off);
    p1 += __shfl_xor(p1, off);
  }
  if (lane == 0){
    float z0 = p0 + bc[0], z1 = p1 + bc[1];
    float m = fmaxf(z0, z1);
    float lse = m + logf(expf(z0 - m) + expf(z1 - m));
    out[(size_t)n * 2 + 0] = z0 - lse;
    out[(size_t)n * 2 + 1] = z1 - lse;
  }
}

// ---------------- host launch ----------------

extern "C" void kernel_launch(void* const* d_in, const int* in_sizes, int n_in,
                              void* d_out, int out_size, void* d_ws, size_t ws_size,
                              hipStream_t stream)
{
  const float* x   = (const float*)d_in[0];
  const int*   ei  = (const int*)d_in[1];
  const float* W1l = (const float*)d_in[2];
  const float* W1r = (const float*)d_in[3];
  const float* b1  = (const float*)d_in[4];
  const float* W2l = (const float*)d_in[5];
  const float* W2r = (const float*)d_in[6];
  const float* b2  = (const float*)d_in[7];
  const float* Wc  = (const float*)d_in[8];
  const float* bc  = (const float*)d_in[9];
  float* out = (float*)d_out;

  const int N = NN, E = NE;
  const int* src = ei;
  const int* dst = ei + E;

  char* ws = (char*)d_ws;
  size_t off = 0;
  auto alloc = [&](size_t bytes) -> void* {
    void* p = ws + off;
    off += (bytes + 255) & ~(size_t)255;
    return p;
  };
  int*   cnt      = (int*)alloc((size_t)N * 4);
  int*   offs     = (int*)alloc((size_t)N * 4);
  int*   cursor   = (int*)alloc((size_t)N * 4);
  float* deginv   = (float*)alloc((size_t)N * 4);
  int*   partials = (int*)alloc(1024);
  int*   bases    = (int*)alloc(1024);
  int*   csr      = (int*)alloc((size_t)E * 4);
  unsigned short* Bt1 = (unsigned short*)alloc((size_t)512 * 256 * 2);
  unsigned short* Bt2 = (unsigned short*)alloc((size_t)256 * 256 * 2);
  unsigned short* xb  = (unsigned short*)alloc((size_t)MPAD * 256 * 2);  // also h (layer-2 input)
  unsigned short* C1  = (unsigned short*)alloc((size_t)MPAD * 512 * 2);  // also C2 + h2

  unsigned short* h  = xb;                                   // alias: xb dead after gemm1
  unsigned short* C2 = C1;                                   // alias: C1 dead after agg1
  float*          h2 = (float*)((char*)C1 + (size_t)MPAD * 256 * 2);  // upper half of C1 region

  (void)in_sizes; (void)n_in; (void)out_size; (void)ws_size;

  hipMemsetAsync(cnt, 0, (size_t)N * 4, stream);

  int nchunk = (N + 1023) / 1024;
  k_degree<<<(E + 255) / 256, 256, 0, stream>>>(dst, cnt, E);
  k_chunk_sum<<<nchunk, 1024, 0, stream>>>(cnt, partials, N);
  k_scan_partials<<<1, 64, 0, stream>>>(partials, bases, nchunk);
  k_chunk_scan<<<nchunk, 1024, 0, stream>>>(cnt, bases, offs, cursor, deginv, N);
  k_fill<<<(E + 255) / 256, 256, 0, stream>>>(src, dst, cursor, csr, E);

  k_cvt<<<MPAD / 8, 256, 0, stream>>>(x, xb);
  k_prep_w<<<512, 256, 0, stream>>>(W1l, W1r, W2l, W2r, Bt1, Bt2);

  // layer 1: C1 = xb @ [W1l|W1r]  (q1 cols 0..255, r1 cols 256..511)
  {
    dim3 g(MPAD / 128, 512 / 128);
    k_gemm<<<g, 256, 0, stream>>>(xb, Bt1, C1, 512);
  }
  k_agg1<<<N / 4, 256, 0, stream>>>(C1, b1, offs, cnt, deginv, csr, h, N);

  // layer 2: C2 = h @ [W2l|W2r]  (p2 cols 0..127, r2 cols 128..255)
  {
    dim3 g(MPAD / 128, 256 / 128);
    k_gemm<<<g, 256, 0, stream>>>(h, Bt2, C2, 256);
  }
  k_agg2<<<N / 4, 256, 0, stream>>>(C2, b2, offs, cnt, deginv, csr, h2, N);

  k_cls<<<N / 4, 256, 0, stream>>>(h2, Wc, bc, out, N);
}

// Round 3
// 372.413 us; speedup vs baseline: 2.2894x; 1.2749x over previous
//
#include <hip/hip_runtime.h>
#include <hip/hip_bf16.h>

#define NN 100000
#define NE 1000000
#define MPAD 100096   // 782*128

typedef __attribute__((ext_vector_type(8))) short bf16x8;
typedef __attribute__((ext_vector_type(4))) float f32x4;
typedef __attribute__((ext_vector_type(8))) unsigned short us8;

static __device__ __forceinline__ float bf2f(unsigned short u){
  unsigned int x = ((unsigned int)u) << 16;
  return __uint_as_float(x);
}
static __device__ __forceinline__ unsigned short f2bf(float f){
  unsigned int x = __float_as_uint(f);
  unsigned int r = (x + 0x7fffu + ((x >> 16) & 1u)) >> 16;
  return (unsigned short)r;
}
static __device__ __forceinline__ void gld16(const void* g, void* l){
  __builtin_amdgcn_global_load_lds((const __attribute__((address_space(1))) void*)g,
                                   (__attribute__((address_space(3))) void*)l, 16, 0, 0);
}

// ---------------- CSR build ----------------

__global__ void k_degree(const int* __restrict__ dst, int* __restrict__ cnt, int E){
  int e = blockIdx.x * blockDim.x + threadIdx.x;
  if (e < E) atomicAdd(&cnt[dst[e]], 1);
}

__global__ void k_chunk_sum(const int* __restrict__ cnt, int* __restrict__ partials, int N){
  __shared__ int sw[16];
  int b = blockIdx.x, t = threadIdx.x;
  int i = b * 1024 + t;
  int v = (i < N) ? cnt[i] : 0;
  #pragma unroll
  for (int off = 32; off; off >>= 1) v += __shfl_xor(v, off);
  int lane = t & 63, w = t >> 6;
  if (lane == 0) sw[w] = v;
  __syncthreads();
  if (t < 16){
    int s = sw[t];
    #pragma unroll
    for (int off = 8; off; off >>= 1) s += __shfl_xor(s, off);
    if (t == 0) partials[b] = s;
  }
}

__global__ void k_scan_partials(const int* __restrict__ partials, int* __restrict__ bases, int nchunk){
  if (threadIdx.x == 0 && blockIdx.x == 0){
    int run = 0;
    for (int j = 0; j < nchunk; j++){ bases[j] = run; run += partials[j]; }
  }
}

__global__ void k_chunk_scan(const int* __restrict__ cnt, const int* __restrict__ bases,
                             int* __restrict__ offs, int* __restrict__ cursor,
                             float* __restrict__ deginv, int N){
  __shared__ int sd[1024];
  int b = blockIdx.x, t = threadIdx.x;
  int i = b * 1024 + t;
  int v = (i < N) ? cnt[i] : 0;
  sd[t] = v;
  __syncthreads();
  for (int off = 1; off < 1024; off <<= 1){
    int x = (t >= off) ? sd[t - off] : 0;
    __syncthreads();
    sd[t] += x;
    __syncthreads();
  }
  if (i < N){
    int excl = bases[b] + sd[t] - v;
    offs[i] = excl;
    cursor[i] = excl;
    deginv[i] = (v > 0) ? (1.0f / (float)v) : 0.0f;
  }
}

__global__ void k_fill(const int* __restrict__ src, const int* __restrict__ dst,
                       int* __restrict__ cursor, int* __restrict__ csr, int E){
  int e = blockIdx.x * blockDim.x + threadIdx.x;
  if (e < E){
    int p = atomicAdd(&cursor[dst[e]], 1);
    csr[p] = src[e];
  }
}

// ---------------- input cast + pad: x f32 -> xb bf16 [MPAD][256] ----------------

__global__ void k_cvt(const float* __restrict__ x, unsigned short* __restrict__ xb){
  size_t i = ((size_t)blockIdx.x * 256 + threadIdx.x) * 8;
  if (i >= (size_t)MPAD * 256) return;
  int row = (int)(i >> 8);
  us8 o;
  if (row < NN){
    const float4* p = (const float4*)(x + i);
    float4 a = p[0], b = p[1];
    o[0]=f2bf(a.x); o[1]=f2bf(a.y); o[2]=f2bf(a.z); o[3]=f2bf(a.w);
    o[4]=f2bf(b.x); o[5]=f2bf(b.y); o[6]=f2bf(b.z); o[7]=f2bf(b.w);
  } else {
    #pragma unroll
    for (int j = 0; j < 8; j++) o[j] = 0;
  }
  *(us8*)(xb + i) = o;
}

// ---------------- weight prep: Bt[n][k] bf16 (transposed, cols concatenated) ----------------

__global__ void k_prep_w(const float* __restrict__ W1l, const float* __restrict__ W1r,
                         const float* __restrict__ W2l, const float* __restrict__ W2r,
                         unsigned short* __restrict__ Bt1, unsigned short* __restrict__ Bt2){
  int i = blockIdx.x * 256 + threadIdx.x;
  if (i < 512 * 256){
    int n = i >> 8, k = i & 255;
    float v = (n < 256) ? W1l[k * 256 + n] : W1r[k * 256 + (n - 256)];
    Bt1[n * 256 + k] = f2bf(v);
  }
  if (i < 256 * 256){
    int n = i >> 8, k = i & 255;
    float v = (n < 128) ? W2l[k * 128 + n] : W2r[k * 128 + (n - 128)];
    Bt2[n * 256 + k] = f2bf(v);
  }
}

// ---------------- MFMA GEMM: C[M][Nout] = A[M][256] @ Bt[Nout][256]^T (all bf16) ----------------

__global__ __launch_bounds__(256)
void k_gemm(const unsigned short* __restrict__ A,
            const unsigned short* __restrict__ Bt,
            unsigned short* __restrict__ C,
            int Nout)
{
  __shared__ __align__(16) unsigned short lA[128 * 64];
  __shared__ __align__(16) unsigned short lB[128 * 64];
  const int t = threadIdx.x;
  const int lane = t & 63, wid = t >> 6;
  const int wm = wid >> 1, wn = wid & 1;
  const int m0 = blockIdx.x * 128;
  const int n0 = blockIdx.y * 128;

  f32x4 acc[4][4] = {};

  const int strow = wid * 32 + (lane >> 3);
  const int sc    = (lane & 7) ^ ((lane >> 3) & 7);

  for (int kt = 0; kt < 4; ++kt){
    __syncthreads();
    #pragma unroll
    for (int s4 = 0; s4 < 4; ++s4){
      int row = strow + s4 * 8;
      gld16(A  + (size_t)(m0 + row) * 256 + kt * 64 + sc * 8, &lA[(wid * 4 + s4) * 512]);
      gld16(Bt + (size_t)(n0 + row) * 256 + kt * 64 + sc * 8, &lB[(wid * 4 + s4) * 512]);
    }
    __syncthreads();
    #pragma unroll
    for (int ks = 0; ks < 2; ++ks){
      bf16x8 av[4], bv[4];
      const int kc = ks * 4 + (lane >> 4);
      #pragma unroll
      for (int m = 0; m < 4; m++){
        int r = wm * 64 + m * 16 + (lane & 15);
        av[m] = *(const bf16x8*)&lA[r * 64 + ((kc ^ (r & 7)) << 3)];
      }
      #pragma unroll
      for (int n = 0; n < 4; n++){
        int c = wn * 64 + n * 16 + (lane & 15);
        bv[n] = *(const bf16x8*)&lB[c * 64 + ((kc ^ (c & 7)) << 3)];
      }
      #pragma unroll
      for (int m = 0; m < 4; m++)
        #pragma unroll
        for (int n = 0; n < 4; n++)
          acc[m][n] = __builtin_amdgcn_mfma_f32_16x16x32_bf16(av[m], bv[n], acc[m][n], 0, 0, 0);
    }
  }

  const int crow0 = m0 + wm * 64 + (lane >> 4) * 4;
  const int ccol0 = n0 + wn * 64 + (lane & 15);
  #pragma unroll
  for (int m = 0; m < 4; m++){
    #pragma unroll
    for (int r = 0; r < 4; r++){
      size_t rowoff = (size_t)(crow0 + m * 16 + r) * Nout;
      #pragma unroll
      for (int n = 0; n < 4; n++)
        C[rowoff + ccol0 + n * 16] = f2bf(acc[m][n][r]);
    }
  }
}

// ---------------- Aggregation 1: h = relu(deginv*agg(q1) + r1 + b1) ----------------
// C1 = [MPAD][512] bf16 (q1|r1). Wave per node; 2 lane-groups of 32, 16B/lane,
// 2 edges/iter, unrolled x2 -> 4 gathers in flight.

__global__ void k_agg1(const unsigned short* __restrict__ C1,
                       const float* __restrict__ b1,
                       const int* __restrict__ offs, const int* __restrict__ cnt,
                       const float* __restrict__ deginv,
                       const int* __restrict__ csr,
                       unsigned short* __restrict__ h, int N)
{
  int wv = threadIdx.x >> 6, lane = threadIdx.x & 63;
  int n = blockIdx.x * 4 + wv;
  if (n >= N) return;
  int beg = offs[n], d = cnt[n];
  const int g = lane >> 5;       // edge-group 0/1
  const int cl = lane & 31;      // cols cl*8..cl*8+7

  float acc[8];
  #pragma unroll
  for (int k = 0; k < 8; k++) acc[k] = 0.f;

  int jj = g;
  for (; jj + 2 < d; jj += 4){
    int s0 = csr[beg + jj];
    int s1 = csr[beg + jj + 2];
    us8 v0 = *(const us8*)(C1 + (size_t)s0 * 512 + cl * 8);
    us8 v1 = *(const us8*)(C1 + (size_t)s1 * 512 + cl * 8);
    #pragma unroll
    for (int k = 0; k < 8; k++) acc[k] += bf2f(v0[k]);
    #pragma unroll
    for (int k = 0; k < 8; k++) acc[k] += bf2f(v1[k]);
  }
  if (jj < d){
    int s = csr[beg + jj];
    us8 v = *(const us8*)(C1 + (size_t)s * 512 + cl * 8);
    #pragma unroll
    for (int k = 0; k < 8; k++) acc[k] += bf2f(v[k]);
  }
  #pragma unroll
  for (int k = 0; k < 8; k++) acc[k] += __shfl_xor(acc[k], 32);

  if (lane < 32){
    float di = deginv[n];
    us8 rv = *(const us8*)(C1 + (size_t)n * 512 + 256 + cl * 8);
    float4 b0 = *(const float4*)(b1 + cl * 8);
    float4 b4 = *(const float4*)(b1 + cl * 8 + 4);
    float bb[8] = {b0.x, b0.y, b0.z, b0.w, b4.x, b4.y, b4.z, b4.w};
    us8 o;
    #pragma unroll
    for (int k = 0; k < 8; k++)
      o[k] = f2bf(fmaxf(acc[k] * di + bf2f(rv[k]) + bb[k], 0.f));
    *(us8*)(h + (size_t)n * 256 + cl * 8) = o;
  }
}

// ---------------- Aggregation 2 + classifier + log_softmax (fused) ----------------
// C2 = [MPAD][256] bf16 (p2|r2). Wave per node; 4 lane-groups of 16, 16B/lane,
// 4 edges/iter, unrolled x2 -> 8 gathers in flight. h2 never materialized.

__global__ void k_agg2cls(const unsigned short* __restrict__ C2,
                          const float* __restrict__ b2,
                          const float* __restrict__ Wc,
                          const float* __restrict__ bc,
                          const int* __restrict__ offs, const int* __restrict__ cnt,
                          const float* __restrict__ deginv,
                          const int* __restrict__ csr,
                          float* __restrict__ out, int N)
{
  int wv = threadIdx.x >> 6, lane = threadIdx.x & 63;
  int n = blockIdx.x * 4 + wv;
  if (n >= N) return;
  int beg = offs[n], d = cnt[n];
  const int g = lane >> 4;       // edge-group 0..3
  const int cl = lane & 15;      // cols cl*8..cl*8+7

  float acc[8];
  #pragma unroll
  for (int k = 0; k < 8; k++) acc[k] = 0.f;

  int jj = g;
  for (; jj + 4 < d; jj += 8){
    int s0 = csr[beg + jj];
    int s1 = csr[beg + jj + 4];
    us8 v0 = *(const us8*)(C2 + (size_t)s0 * 256 + cl * 8);
    us8 v1 = *(const us8*)(C2 + (size_t)s1 * 256 + cl * 8);
    #pragma unroll
    for (int k = 0; k < 8; k++) acc[k] += bf2f(v0[k]);
    #pragma unroll
    for (int k = 0; k < 8; k++) acc[k] += bf2f(v1[k]);
  }
  if (jj < d){
    int s = csr[beg + jj];
    us8 v = *(const us8*)(C2 + (size_t)s * 256 + cl * 8);
    #pragma unroll
    for (int k = 0; k < 8; k++) acc[k] += bf2f(v[k]);
  }
  #pragma unroll
  for (int k = 0; k < 8; k++){
    acc[k] += __shfl_xor(acc[k], 16);
    acc[k] += __shfl_xor(acc[k], 32);
  }

  // epilogue: all lanes compute (groups redundant), lane 0 writes
  float di = deginv[n];
  us8 rv = *(const us8*)(C2 + (size_t)n * 256 + 128 + cl * 8);
  float4 b0 = *(const float4*)(b2 + cl * 8);
  float4 b4 = *(const float4*)(b2 + cl * 8 + 4);
  float bb[8] = {b0.x, b0.y, b0.z, b0.w, b4.x, b4.y, b4.z, b4.w};
  float p0 = 0.f, p1 = 0.f;
  #pragma unroll
  for (int k = 0; k < 8; k += 2){
    float h0 = fmaxf(acc[k]     * di + bf2f(rv[k])     + bb[k],     0.f);
    float h1 = fmaxf(acc[k + 1] * di + bf2f(rv[k + 1]) + bb[k + 1], 0.f);
    float4 w = *(const float4*)(Wc + (cl * 8 + k) * 2);
    p0 += h0 * w.x + h1 * w.z;
    p1 += h0 * w.y + h1 * w.w;
  }
  #pragma unroll
  for (int off = 8; off; off >>= 1){
    p0 += __shfl_xor(p0, off);
    p1 += __shfl_xor(p1, off);
  }
  if (lane == 0){
    float z0 = p0 + bc[0], z1 = p1 + bc[1];
    float m = fmaxf(z0, z1);
    float lse = m + logf(expf(z0 - m) + expf(z1 - m));
    out[(size_t)n * 2 + 0] = z0 - lse;
    out[(size_t)n * 2 + 1] = z1 - lse;
  }
}

// ---------------- host launch ----------------

extern "C" void kernel_launch(void* const* d_in, const int* in_sizes, int n_in,
                              void* d_out, int out_size, void* d_ws, size_t ws_size,
                              hipStream_t stream)
{
  const float* x   = (const float*)d_in[0];
  const int*   ei  = (const int*)d_in[1];
  const float* W1l = (const float*)d_in[2];
  const float* W1r = (const float*)d_in[3];
  const float* b1  = (const float*)d_in[4];
  const float* W2l = (const float*)d_in[5];
  const float* W2r = (const float*)d_in[6];
  const float* b2  = (const float*)d_in[7];
  const float* Wc  = (const float*)d_in[8];
  const float* bc  = (const float*)d_in[9];
  float* out = (float*)d_out;

  const int N = NN, E = NE;
  const int* src = ei;
  const int* dst = ei + E;

  char* ws = (char*)d_ws;
  size_t off = 0;
  auto alloc = [&](size_t bytes) -> void* {
    void* p = ws + off;
    off += (bytes + 255) & ~(size_t)255;
    return p;
  };
  int*   cnt      = (int*)alloc((size_t)N * 4);
  int*   offs     = (int*)alloc((size_t)N * 4);
  int*   cursor   = (int*)alloc((size_t)N * 4);
  float* deginv   = (float*)alloc((size_t)N * 4);
  int*   partials = (int*)alloc(1024);
  int*   bases    = (int*)alloc(1024);
  int*   csr      = (int*)alloc((size_t)E * 4);
  unsigned short* Bt1 = (unsigned short*)alloc((size_t)512 * 256 * 2);
  unsigned short* Bt2 = (unsigned short*)alloc((size_t)256 * 256 * 2);
  unsigned short* xb  = (unsigned short*)alloc((size_t)MPAD * 256 * 2);
  unsigned short* C1  = (unsigned short*)alloc((size_t)MPAD * 512 * 2);

  unsigned short* h  = xb;   // alias: xb dead after gemm1
  unsigned short* C2 = C1;   // alias: C1 dead after agg1

  (void)in_sizes; (void)n_in; (void)out_size; (void)ws_size;

  hipMemsetAsync(cnt, 0, (size_t)N * 4, stream);

  int nchunk = (N + 1023) / 1024;
  k_degree<<<(E + 255) / 256, 256, 0, stream>>>(dst, cnt, E);
  k_chunk_sum<<<nchunk, 1024, 0, stream>>>(cnt, partials, N);
  k_scan_partials<<<1, 64, 0, stream>>>(partials, bases, nchunk);
  k_chunk_scan<<<nchunk, 1024, 0, stream>>>(cnt, bases, offs, cursor, deginv, N);
  k_fill<<<(E + 255) / 256, 256, 0, stream>>>(src, dst, cursor, csr, E);

  k_cvt<<<MPAD / 8, 256, 0, stream>>>(x, xb);
  k_prep_w<<<512, 256, 0, stream>>>(W1l, W1r, W2l, W2r, Bt1, Bt2);

  // layer 1: C1 = xb @ [W1l|W1r]
  {
    dim3 g(MPAD / 128, 512 / 128);
    k_gemm<<<g, 256, 0, stream>>>(xb, Bt1, C1, 512);
  }
  k_agg1<<<N / 4, 256, 0, stream>>>(C1, b1, offs, cnt, deginv, csr, h, N);

  // layer 2: C2 = h @ [W2l|W2r]
  {
    dim3 g(MPAD / 128, 256 / 128);
    k_gemm<<<g, 256, 0, stream>>>(h, Bt2, C2, 256);
  }
  // agg2 + classifier + log_softmax fused
  k_agg2cls<<<N / 4, 256, 0, stream>>>(C2, b2, Wc, bc, offs, cnt, deginv, csr, out, N);
}

// Round 5
// 368.409 us; speedup vs baseline: 2.3143x; 1.0109x over previous
//
#include <hip/hip_runtime.h>
#include <hip/hip_bf16.h>

#define NN 100000
#define NE 1000000
#define MPAD 100096   // 782*128

typedef __attribute__((ext_vector_type(8))) short bf16x8;
typedef __attribute__((ext_vector_type(4))) float f32x4;
typedef __attribute__((ext_vector_type(8))) unsigned short us8;

static __device__ __forceinline__ float bf2f(unsigned short u){
  unsigned int x = ((unsigned int)u) << 16;
  return __uint_as_float(x);
}
static __device__ __forceinline__ unsigned short f2bf(float f){
  unsigned int x = __float_as_uint(f);
  unsigned int r = (x + 0x7fffu + ((x >> 16) & 1u)) >> 16;
  return (unsigned short)r;
}
static __device__ __forceinline__ void gld16(const void* g, void* l){
  __builtin_amdgcn_global_load_lds((const __attribute__((address_space(1))) void*)g,
                                   (__attribute__((address_space(3))) void*)l, 16, 0, 0);
}

// ---------------- CSR build ----------------

__global__ void k_degree(const int* __restrict__ dst, int* __restrict__ cnt, int E){
  int e = blockIdx.x * blockDim.x + threadIdx.x;
  if (e < E) atomicAdd(&cnt[dst[e]], 1);
}

__global__ void k_chunk_sum(const int* __restrict__ cnt, int* __restrict__ partials, int N){
  __shared__ int sw[16];
  int b = blockIdx.x, t = threadIdx.x;
  int i = b * 1024 + t;
  int v = (i < N) ? cnt[i] : 0;
  #pragma unroll
  for (int off = 32; off; off >>= 1) v += __shfl_xor(v, off);
  int lane = t & 63, w = t >> 6;
  if (lane == 0) sw[w] = v;
  __syncthreads();
  if (t < 16){
    int s = sw[t];
    #pragma unroll
    for (int off = 8; off; off >>= 1) s += __shfl_xor(s, off);
    if (t == 0) partials[b] = s;
  }
}

__global__ void k_scan_partials(const int* __restrict__ partials, int* __restrict__ bases, int nchunk){
  if (threadIdx.x == 0 && blockIdx.x == 0){
    int run = 0;
    for (int j = 0; j < nchunk; j++){ bases[j] = run; run += partials[j]; }
  }
}

__global__ void k_chunk_scan(const int* __restrict__ cnt, const int* __restrict__ bases,
                             int* __restrict__ offs, int* __restrict__ cursor,
                             float* __restrict__ deginv, int N){
  __shared__ int sd[1024];
  int b = blockIdx.x, t = threadIdx.x;
  int i = b * 1024 + t;
  int v = (i < N) ? cnt[i] : 0;
  sd[t] = v;
  __syncthreads();
  for (int off = 1; off < 1024; off <<= 1){
    int x = (t >= off) ? sd[t - off] : 0;
    __syncthreads();
    sd[t] += x;
    __syncthreads();
  }
  if (i < N){
    int excl = bases[b] + sd[t] - v;
    offs[i] = excl;
    cursor[i] = excl;
    deginv[i] = (v > 0) ? (1.0f / (float)v) : 0.0f;
  }
}

__global__ void k_fill(const int* __restrict__ src, const int* __restrict__ dst,
                       int* __restrict__ cursor, int* __restrict__ csr, int E){
  int e = blockIdx.x * blockDim.x + threadIdx.x;
  if (e < E){
    int p = atomicAdd(&cursor[dst[e]], 1);
    csr[p] = src[e];
  }
}

// ---------------- input cast + pad: x f32 -> xb bf16 [MPAD][256] ----------------

__global__ void k_cvt(const float* __restrict__ x, unsigned short* __restrict__ xb){
  size_t i = ((size_t)blockIdx.x * 256 + threadIdx.x) * 8;
  if (i >= (size_t)MPAD * 256) return;
  int row = (int)(i >> 8);
  us8 o;
  if (row < NN){
    const float4* p = (const float4*)(x + i);
    float4 a = p[0], b = p[1];
    o[0]=f2bf(a.x); o[1]=f2bf(a.y); o[2]=f2bf(a.z); o[3]=f2bf(a.w);
    o[4]=f2bf(b.x); o[5]=f2bf(b.y); o[6]=f2bf(b.z); o[7]=f2bf(b.w);
  } else {
    #pragma unroll
    for (int j = 0; j < 8; j++) o[j] = 0;
  }
  *(us8*)(xb + i) = o;
}

// ---------------- weight prep: Bt[n][k] bf16 (transposed, cols concatenated) ----------------

__global__ void k_prep_w(const float* __restrict__ W1l, const float* __restrict__ W1r,
                         const float* __restrict__ W2l, const float* __restrict__ W2r,
                         unsigned short* __restrict__ Bt1, unsigned short* __restrict__ Bt2){
  int i = blockIdx.x * 256 + threadIdx.x;
  if (i < 512 * 256){
    int n = i >> 8, k = i & 255;
    float v = (n < 256) ? W1l[k * 256 + n] : W1r[k * 256 + (n - 256)];
    Bt1[n * 256 + k] = f2bf(v);
  }
  if (i < 256 * 256){
    int n = i >> 8, k = i & 255;
    float v = (n < 128) ? W2l[k * 128 + n] : W2r[k * 128 + (n - 128)];
    Bt2[n * 256 + k] = f2bf(v);
  }
}

// ---------------- MFMA GEMM: C[M][Nout] = A[M][256] @ Bt[Nout][256]^T (all bf16) ----------------

__global__ __launch_bounds__(256)
void k_gemm(const unsigned short* __restrict__ A,
            const unsigned short* __restrict__ Bt,
            unsigned short* __restrict__ C,
            int Nout)
{
  __shared__ __align__(16) unsigned short lA[128 * 64];
  __shared__ __align__(16) unsigned short lB[128 * 64];
  const int t = threadIdx.x;
  const int lane = t & 63, wid = t >> 6;
  const int wm = wid >> 1, wn = wid & 1;
  const int m0 = blockIdx.x * 128;
  const int n0 = blockIdx.y * 128;

  f32x4 acc[4][4] = {};

  const int strow = wid * 32 + (lane >> 3);
  const int sc    = (lane & 7) ^ ((lane >> 3) & 7);

  for (int kt = 0; kt < 4; ++kt){
    __syncthreads();
    #pragma unroll
    for (int s4 = 0; s4 < 4; ++s4){
      int row = strow + s4 * 8;
      gld16(A  + (size_t)(m0 + row) * 256 + kt * 64 + sc * 8, &lA[(wid * 4 + s4) * 512]);
      gld16(Bt + (size_t)(n0 + row) * 256 + kt * 64 + sc * 8, &lB[(wid * 4 + s4) * 512]);
    }
    __syncthreads();
    #pragma unroll
    for (int ks = 0; ks < 2; ++ks){
      bf16x8 av[4], bv[4];
      const int kc = ks * 4 + (lane >> 4);
      #pragma unroll
      for (int m = 0; m < 4; m++){
        int r = wm * 64 + m * 16 + (lane & 15);
        av[m] = *(const bf16x8*)&lA[r * 64 + ((kc ^ (r & 7)) << 3)];
      }
      #pragma unroll
      for (int n = 0; n < 4; n++){
        int c = wn * 64 + n * 16 + (lane & 15);
        bv[n] = *(const bf16x8*)&lB[c * 64 + ((kc ^ (c & 7)) << 3)];
      }
      #pragma unroll
      for (int m = 0; m < 4; m++)
        #pragma unroll
        for (int n = 0; n < 4; n++)
          acc[m][n] = __builtin_amdgcn_mfma_f32_16x16x32_bf16(av[m], bv[n], acc[m][n], 0, 0, 0);
    }
  }

  const int crow0 = m0 + wm * 64 + (lane >> 4) * 4;
  const int ccol0 = n0 + wn * 64 + (lane & 15);
  #pragma unroll
  for (int m = 0; m < 4; m++){
    #pragma unroll
    for (int r = 0; r < 4; r++){
      size_t rowoff = (size_t)(crow0 + m * 16 + r) * Nout;
      #pragma unroll
      for (int n = 0; n < 4; n++)
        C[rowoff + ccol0 + n * 16] = f2bf(acc[m][n][r]);
    }
  }
}

// ---------------- Aggregation 1: h = relu(deginv*agg(q1) + r1 + b1) ----------------
// C1 = [MPAD][512] bf16 (q1|r1). Wave per node; CSR window (<=64 edges)
// preloaded once, broadcast via __shfl. UNIFORM trip count across lane
// groups (shfl executes with all lanes active); gathers unconditional
// (safe index 0 for tail slots), only accumulation predicated.
// 2 lane-groups of 32, 16B/lane, 4 edges/group-iter -> 4 gathers in flight.

__global__ void k_agg1(const unsigned short* __restrict__ C1,
                       const float* __restrict__ b1,
                       const int* __restrict__ offs, const int* __restrict__ cnt,
                       const float* __restrict__ deginv,
                       const int* __restrict__ csr,
                       unsigned short* __restrict__ h, int N)
{
  int wv = threadIdx.x >> 6, lane = threadIdx.x & 63;
  int n = blockIdx.x * 4 + wv;
  if (n >= N) return;
  int beg = offs[n], d = cnt[n];
  const int g = lane >> 5;       // edge-group 0/1
  const int cl = lane & 31;      // cols cl*8..cl*8+7

  float acc[8];
  #pragma unroll
  for (int k = 0; k < 8; k++) acc[k] = 0.f;

  for (int w0 = 0; w0 < d; w0 += 64){
    int wlen = min(d - w0, 64);
    int idx = 0;
    if (lane < wlen) idx = csr[beg + w0 + lane];
    int nIter = (wlen + 7) >> 3;               // uniform across the wave
    for (int t = 0; t < nIter; t++){
      int e0 = t * 8 + g;                      // group g edges: e0, e0+2, e0+4, e0+6
      int s0 = __shfl(idx, e0);
      int s1 = __shfl(idx, e0 + 2);
      int s2 = __shfl(idx, e0 + 4);
      int s3 = __shfl(idx, e0 + 6);
      us8 v0 = *(const us8*)(C1 + (size_t)s0 * 512 + cl * 8);
      us8 v1 = *(const us8*)(C1 + (size_t)s1 * 512 + cl * 8);
      us8 v2 = *(const us8*)(C1 + (size_t)s2 * 512 + cl * 8);
      us8 v3 = *(const us8*)(C1 + (size_t)s3 * 512 + cl * 8);
      if (e0 < wlen){
        #pragma unroll
        for (int k = 0; k < 8; k++) acc[k] += bf2f(v0[k]);
      }
      if (e0 + 2 < wlen){
        #pragma unroll
        for (int k = 0; k < 8; k++) acc[k] += bf2f(v1[k]);
      }
      if (e0 + 4 < wlen){
        #pragma unroll
        for (int k = 0; k < 8; k++) acc[k] += bf2f(v2[k]);
      }
      if (e0 + 6 < wlen){
        #pragma unroll
        for (int k = 0; k < 8; k++) acc[k] += bf2f(v3[k]);
      }
    }
  }
  #pragma unroll
  for (int k = 0; k < 8; k++) acc[k] += __shfl_xor(acc[k], 32);

  if (lane < 32){
    float di = deginv[n];
    us8 rv = *(const us8*)(C1 + (size_t)n * 512 + 256 + cl * 8);
    float4 b0 = *(const float4*)(b1 + cl * 8);
    float4 b4 = *(const float4*)(b1 + cl * 8 + 4);
    float bb[8] = {b0.x, b0.y, b0.z, b0.w, b4.x, b4.y, b4.z, b4.w};
    us8 o;
    #pragma unroll
    for (int k = 0; k < 8; k++)
      o[k] = f2bf(fmaxf(acc[k] * di + bf2f(rv[k]) + bb[k], 0.f));
    *(us8*)(h + (size_t)n * 256 + cl * 8) = o;
  }
}

// ---------------- Aggregation 2 + classifier + log_softmax (fused) ----------------
// C2 = [MPAD][256] bf16 (p2|r2). Same uniform-trip-count shfl-broadcast scheme.
// 4 lane-groups of 16, 16B/lane, 4 edges/group-iter -> 4 gathers in flight.

__global__ void k_agg2cls(const unsigned short* __restrict__ C2,
                          const float* __restrict__ b2,
                          const float* __restrict__ Wc,
                          const float* __restrict__ bc,
                          const int* __restrict__ offs, const int* __restrict__ cnt,
                          const float* __restrict__ deginv,
                          const int* __restrict__ csr,
                          float* __restrict__ out, int N)
{
  int wv = threadIdx.x >> 6, lane = threadIdx.x & 63;
  int n = blockIdx.x * 4 + wv;
  if (n >= N) return;
  int beg = offs[n], d = cnt[n];
  const int g = lane >> 4;       // edge-group 0..3
  const int cl = lane & 15;      // cols cl*8..cl*8+7

  float acc[8];
  #pragma unroll
  for (int k = 0; k < 8; k++) acc[k] = 0.f;

  for (int w0 = 0; w0 < d; w0 += 64){
    int wlen = min(d - w0, 64);
    int idx = 0;
    if (lane < wlen) idx = csr[beg + w0 + lane];
    int nIter = (wlen + 15) >> 4;              // uniform across the wave
    for (int t = 0; t < nIter; t++){
      int e0 = t * 16 + g;                     // group g edges: e0, +4, +8, +12
      int s0 = __shfl(idx, e0);
      int s1 = __shfl(idx, e0 + 4);
      int s2 = __shfl(idx, e0 + 8);
      int s3 = __shfl(idx, e0 + 12);
      us8 v0 = *(const us8*)(C2 + (size_t)s0 * 256 + cl * 8);
      us8 v1 = *(const us8*)(C2 + (size_t)s1 * 256 + cl * 8);
      us8 v2 = *(const us8*)(C2 + (size_t)s2 * 256 + cl * 8);
      us8 v3 = *(const us8*)(C2 + (size_t)s3 * 256 + cl * 8);
      if (e0 < wlen){
        #pragma unroll
        for (int k = 0; k < 8; k++) acc[k] += bf2f(v0[k]);
      }
      if (e0 + 4 < wlen){
        #pragma unroll
        for (int k = 0; k < 8; k++) acc[k] += bf2f(v1[k]);
      }
      if (e0 + 8 < wlen){
        #pragma unroll
        for (int k = 0; k < 8; k++) acc[k] += bf2f(v2[k]);
      }
      if (e0 + 12 < wlen){
        #pragma unroll
        for (int k = 0; k < 8; k++) acc[k] += bf2f(v3[k]);
      }
    }
  }
  #pragma unroll
  for (int k = 0; k < 8; k++){
    acc[k] += __shfl_xor(acc[k], 16);
    acc[k] += __shfl_xor(acc[k], 32);
  }

  // epilogue: all lanes compute (groups redundant), lane 0 writes
  float di = deginv[n];
  us8 rv = *(const us8*)(C2 + (size_t)n * 256 + 128 + cl * 8);
  float4 b0 = *(const float4*)(b2 + cl * 8);
  float4 b4 = *(const float4*)(b2 + cl * 8 + 4);
  float bb[8] = {b0.x, b0.y, b0.z, b0.w, b4.x, b4.y, b4.z, b4.w};
  float p0 = 0.f, p1 = 0.f;
  #pragma unroll
  for (int k = 0; k < 8; k += 2){
    float h0 = fmaxf(acc[k]     * di + bf2f(rv[k])     + bb[k],     0.f);
    float h1 = fmaxf(acc[k + 1] * di + bf2f(rv[k + 1]) + bb[k + 1], 0.f);
    float4 w = *(const float4*)(Wc + (cl * 8 + k) * 2);
    p0 += h0 * w.x + h1 * w.z;
    p1 += h0 * w.y + h1 * w.w;
  }
  #pragma unroll
  for (int off = 8; off; off >>= 1){
    p0 += __shfl_xor(p0, off);
    p1 += __shfl_xor(p1, off);
  }
  if (lane == 0){
    float z0 = p0 + bc[0], z1 = p1 + bc[1];
    float m = fmaxf(z0, z1);
    float lse = m + logf(expf(z0 - m) + expf(z1 - m));
    out[(size_t)n * 2 + 0] = z0 - lse;
    out[(size_t)n * 2 + 1] = z1 - lse;
  }
}

// ---------------- host launch ----------------

extern "C" void kernel_launch(void* const* d_in, const int* in_sizes, int n_in,
                              void* d_out, int out_size, void* d_ws, size_t ws_size,
                              hipStream_t stream)
{
  const float* x   = (const float*)d_in[0];
  const int*   ei  = (const int*)d_in[1];
  const float* W1l = (const float*)d_in[2];
  const float* W1r = (const float*)d_in[3];
  const float* b1  = (const float*)d_in[4];
  const float* W2l = (const float*)d_in[5];
  const float* W2r = (const float*)d_in[6];
  const float* b2  = (const float*)d_in[7];
  const float* Wc  = (const float*)d_in[8];
  const float* bc  = (const float*)d_in[9];
  float* out = (float*)d_out;

  const int N = NN, E = NE;
  const int* src = ei;
  const int* dst = ei + E;

  char* ws = (char*)d_ws;
  size_t off = 0;
  auto alloc = [&](size_t bytes) -> void* {
    void* p = ws + off;
    off += (bytes + 255) & ~(size_t)255;
    return p;
  };
  int*   cnt      = (int*)alloc((size_t)N * 4);
  int*   offs     = (int*)alloc((size_t)N * 4);
  int*   cursor   = (int*)alloc((size_t)N * 4);
  float* deginv   = (float*)alloc((size_t)N * 4);
  int*   partials = (int*)alloc(1024);
  int*   bases    = (int*)alloc(1024);
  int*   csr      = (int*)alloc((size_t)E * 4);
  unsigned short* Bt1 = (unsigned short*)alloc((size_t)512 * 256 * 2);
  unsigned short* Bt2 = (unsigned short*)alloc((size_t)256 * 256 * 2);
  unsigned short* xb  = (unsigned short*)alloc((size_t)MPAD * 256 * 2);
  unsigned short* C1  = (unsigned short*)alloc((size_t)MPAD * 512 * 2);

  unsigned short* h  = xb;   // alias: xb dead after gemm1
  unsigned short* C2 = C1;   // alias: C1 dead after agg1

  (void)in_sizes; (void)n_in; (void)out_size; (void)ws_size;

  hipMemsetAsync(cnt, 0, (size_t)N * 4, stream);

  int nchunk = (N + 1023) / 1024;
  k_degree<<<(E + 255) / 256, 256, 0, stream>>>(dst, cnt, E);
  k_chunk_sum<<<nchunk, 1024, 0, stream>>>(cnt, partials, N);
  k_scan_partials<<<1, 64, 0, stream>>>(partials, bases, nchunk);
  k_chunk_scan<<<nchunk, 1024, 0, stream>>>(cnt, bases, offs, cursor, deginv, N);
  k_fill<<<(E + 255) / 256, 256, 0, stream>>>(src, dst, cursor, csr, E);

  k_cvt<<<MPAD / 8, 256, 0, stream>>>(x, xb);
  k_prep_w<<<512, 256, 0, stream>>>(W1l, W1r, W2l, W2r, Bt1, Bt2);

  // layer 1: C1 = xb @ [W1l|W1r]
  {
    dim3 g(MPAD / 128, 512 / 128);
    k_gemm<<<g, 256, 0, stream>>>(xb, Bt1, C1, 512);
  }
  k_agg1<<<N / 4, 256, 0, stream>>>(C1, b1, offs, cnt, deginv, csr, h, N);

  // layer 2: C2 = h @ [W2l|W2r]
  {
    dim3 g(MPAD / 128, 256 / 128);
    k_gemm<<<g, 256, 0, stream>>>(h, Bt2, C2, 256);
  }
  // agg2 + classifier + log_softmax fused
  k_agg2cls<<<N / 4, 256, 0, stream>>>(C2, b2, Wc, bc, offs, cnt, deginv, csr, out, N);
}